// Round 1
// 671.341 us; speedup vs baseline: 1.0108x; 1.0108x over previous
//
#include <hip/hip_runtime.h>
#include <hip/hip_bf16.h>

#define NN   50000
#define NE   800000
#define MP   3
#define DIN  128
#define DF   256     // HEADS*OUT_DIM
#define NH   8
#define HID  128
#define NC   (MP*NN)              // 150000
#define SCAN_NB ((NC + 255)/256)  // 586

typedef unsigned short u16;
typedef unsigned int   u32;
typedef __attribute__((ext_vector_type(8))) short bf16x8;   // MFMA A/B frag
typedef __attribute__((ext_vector_type(4))) float f32x4;    // MFMA C/D frag
typedef __attribute__((ext_vector_type(2))) float f32x2;    // pk-math pair

__device__ __forceinline__ float bf2f(u16 u) {
    return __uint_as_float(((u32)u) << 16);
}
__device__ __forceinline__ u16 f2bf(float f) {
    u32 x = __float_as_uint(f);
    u32 r = x + 0x7fffu + ((x >> 16) & 1u);   // round-to-nearest-even
    return (u16)(r >> 16);
}
__device__ __forceinline__ f32x2 bfp(u32 u) {   // unpack bf16 pair -> f32x2
    f32x2 r;
    r.x = __uint_as_float(u << 16);
    r.y = __uint_as_float(u & 0xffff0000u);
    return r;
}
__device__ __forceinline__ float tanh_fast(float x) {
    float c = fminf(fmaxf(x, -15.f), 15.f);
    float t = __expf(2.f * c);
    return (t - 1.f) / (t + 1.f);
}

// ---------------------------------------------------------------------------
// 0) fused: converts (h->hb, Wg->WgT, W1->W1T, WAL) + edge count w/ rank.
//    cvt blocks [0, CVT_NB); count blocks [CVT_NB, CVT_NB + 3*CNT_NB).
// ---------------------------------------------------------------------------
#define CVT_H_N   (NN * DIN / 8)          // 800000
#define CVT_WG_N  (MP * DF * DIN)         // 98304
#define CVT_W1_N  (HID * DF)              // 32768
#define CVT_WAL_N (MP * 16 * DIN)         // 6144
#define CVT_TOT_N (CVT_H_N + CVT_WG_N + CVT_W1_N + CVT_WAL_N)   // 937216
#define CVT_NB    ((CVT_TOT_N + 255) / 256)                     // 3661
#define CNT_NB    ((NE + 255) / 256)                            // 3125
__global__ __launch_bounds__(256) void k_cvt_count(
    const float* __restrict__ h, const float* __restrict__ Wg, const float* __restrict__ W1,
    const float* __restrict__ al, const float* __restrict__ ar,
    u16* __restrict__ hb, u16* __restrict__ WgT, u16* __restrict__ W1T, u16* __restrict__ WALT,
    const int* __restrict__ dst, int* __restrict__ counts, int* __restrict__ rank)
{
    if (blockIdx.x >= CVT_NB) {           // edge-count path
        int b = blockIdx.x - CVT_NB;
        int m = b / CNT_NB;
        int e = (b - m * CNT_NB) * 256 + threadIdx.x;
        if (e < NE) {
            int idx = m * NN + dst[(size_t)m * NE + e];
            rank[(size_t)m * NE + e] = atomicAdd(&counts[idx], 1);
        }
        return;
    }
    int gid = blockIdx.x * 256 + threadIdx.x;
    if (gid < CVT_H_N) {
        size_t i8 = (size_t)gid * 8;
        float4 a = *(const float4*)(h + i8);
        float4 b = *(const float4*)(h + i8 + 4);
        uint4 o;
        o.x = (u32)f2bf(a.x) | ((u32)f2bf(a.y) << 16);
        o.y = (u32)f2bf(a.z) | ((u32)f2bf(a.w) << 16);
        o.z = (u32)f2bf(b.x) | ((u32)f2bf(b.y) << 16);
        o.w = (u32)f2bf(b.z) | ((u32)f2bf(b.w) << 16);
        *(uint4*)(hb + i8) = o;
    } else if (gid < CVT_H_N + CVT_WG_N) {
        int g = gid - CVT_H_N;
        int k = g % DIN, n = (g / DIN) % DF, m = g / (DIN * DF);
        WgT[g] = f2bf(Wg[((size_t)m * DIN + k) * DF + n]);
    } else if (gid < CVT_H_N + CVT_WG_N + CVT_W1_N) {
        int g = gid - CVT_H_N - CVT_WG_N;
        int k = g % DF, n = g / DF;
        W1T[g] = f2bf(W1[(size_t)k * HID + n]);
    } else if (gid < CVT_TOT_N) {
        int g = gid - CVT_H_N - CVT_WG_N - CVT_W1_N;
        int k = g & (DIN - 1), c = (g >> 7) & 15, m = g >> 11;
        int hh = c & 7;
        const float* a  = (c < 8 ? al : ar) + ((size_t)m * NH + hh) * 32;
        const float* wg = Wg + ((size_t)m * DIN + k) * DF + 32 * hh;
        float s = 0.f;
#pragma unroll
        for (int d = 0; d < 32; d++) s += wg[d] * a[d];
        WALT[g] = f2bf(s);
    }
}

// ---------------------------------------------------------------------------
// 1) feat[m] = h @ W_gat[m] via MFMA 16x16x32 bf16; wave does 16x256 strip,
//    plus one extra col-block vs WALT producing el/er (fp32) in the epilogue.
// ---------------------------------------------------------------------------
__global__ __launch_bounds__(256) void k_gemm_feat(
    const u16* __restrict__ hb, const u16* __restrict__ WgT, const u16* __restrict__ WALT,
    u16* __restrict__ feat, float* __restrict__ el, float* __restrict__ er)
{
    const int tid = threadIdx.x, lane = tid & 63, wid = tid >> 6;
    const int quad = lane >> 4, l16 = lane & 15;
    const int m    = blockIdx.y;
    const int row0 = blockIdx.x * 64 + wid * 16;

    const int arow = row0 + l16;
    const int arc  = arow < NN ? arow : NN - 1;
    const u16* ab = hb + (size_t)arc * DIN + quad * 8;
    bf16x8 afrag[4];
#pragma unroll
    for (int ks = 0; ks < 4; ks++) afrag[ks] = *(const bf16x8*)(ab + ks * 32);

    const u16* bb0 = WgT + ((size_t)m * DF + l16) * DIN + quad * 8;
    f32x4 acc[16];
#pragma unroll
    for (int nt = 0; nt < 16; nt++) { acc[nt][0]=0.f; acc[nt][1]=0.f; acc[nt][2]=0.f; acc[nt][3]=0.f; }

#pragma unroll
    for (int nt = 0; nt < 16; nt++) {
        const u16* bb = bb0 + (size_t)nt * 16 * DIN;
#pragma unroll
        for (int ks = 0; ks < 4; ks++) {
            bf16x8 bfrag = *(const bf16x8*)(bb + ks * 32);
            acc[nt] = __builtin_amdgcn_mfma_f32_16x16x32_bf16(afrag[ks], bfrag, acc[nt], 0, 0, 0);
        }
    }
    // extra col-block: el/er
    f32x4 acce; acce[0]=0.f; acce[1]=0.f; acce[2]=0.f; acce[3]=0.f;
    {
        const u16* eb = WALT + ((size_t)m * 16 + l16) * DIN + quad * 8;
#pragma unroll
        for (int ks = 0; ks < 4; ks++) {
            bf16x8 bfrag = *(const bf16x8*)(eb + ks * 32);
            acce = __builtin_amdgcn_mfma_f32_16x16x32_bf16(afrag[ks], bfrag, acce, 0, 0, 0);
        }
    }
    const int rbase = row0 + quad * 4;
#pragma unroll
    for (int nt = 0; nt < 16; nt++)
#pragma unroll
        for (int r = 0; r < 4; r++) {
            int gr = rbase + r;
            if (gr < NN)
                feat[((size_t)m * NN + gr) * DF + nt * 16 + l16] = f2bf(acc[nt][r]);
        }
#pragma unroll
    for (int r = 0; r < 4; r++) {
        int gr = rbase + r;
        if (gr < NN) {
            if (l16 < 8) el[((size_t)m * NN + gr) * NH + l16]       = acce[r];
            else         er[((size_t)m * NN + gr) * NH + (l16 - 8)] = acce[r];
        }
    }
}

// ---------------------------------------------------------------------------
// 3) scan (2 kernels; boff add folded into consumers) + rank-based scatter.
// ---------------------------------------------------------------------------
__global__ void k_scan_a(const int* __restrict__ counts, int* __restrict__ rs, int* __restrict__ bsum) {
    __shared__ int s[256];
    int tid = threadIdx.x, g = blockIdx.x * 256 + tid;
    int v = (g < NC) ? counts[g] : 0;
    s[tid] = v; __syncthreads();
    for (int off = 1; off < 256; off <<= 1) {
        int u = (tid >= off) ? s[tid - off] : 0;
        __syncthreads();
        s[tid] += u;
        __syncthreads();
    }
    if (g < NC) rs[g] = s[tid] - v;
    if (tid == 255) bsum[blockIdx.x] = s[255];
}

__global__ void k_scan_b(const int* __restrict__ bsum, int* __restrict__ boff) {
    __shared__ int s[1024];
    int tid = threadIdx.x;
    int v = (tid < SCAN_NB) ? bsum[tid] : 0;
    s[tid] = v; __syncthreads();
    for (int off = 1; off < 1024; off <<= 1) {
        int u = (tid >= off) ? s[tid - off] : 0;
        __syncthreads();
        s[tid] += u;
        __syncthreads();
    }
    if (tid < SCAN_NB) boff[tid] = s[tid] - v;
}

__global__ void k_scatter(const int* __restrict__ src, const int* __restrict__ dst,
                          const int* __restrict__ rs, const int* __restrict__ boff,
                          const int* __restrict__ rank, int* __restrict__ src_csr) {
    int e = blockIdx.x * 256 + threadIdx.x, m = blockIdx.y;
    if (e >= NE) return;
    int idx = m * NN + dst[(size_t)m * NE + e];
    int pos = rs[idx] + boff[idx >> 8] + rank[(size_t)m * NE + e];
    src_csr[pos] = src[(size_t)m * NE + e];
}

// ---------------------------------------------------------------------------
// 4) Destination-centric GAT, single pass. Wave-uniform CSR walk is forced
//    into SGPRs via readfirstlane: cs[] loads become SMEM, all gather address
//    arithmetic becomes SALU (saddr + loop-invariant voffset), VALU keeps only
//    leaky/exp/unpack/pk_fma. 8-deep unroll for outstanding gathers.
// ---------------------------------------------------------------------------
__global__ __launch_bounds__(256) void k_node(
    const int* __restrict__ src_csr, const int* __restrict__ rs, const int* __restrict__ boff,
    const int* __restrict__ counts,
    const float* __restrict__ el, const float* __restrict__ er,
    const u16* __restrict__ feat, const float* __restrict__ bias, u16* __restrict__ z)
{
    const int lane = threadIdx.x & 63, wid = threadIdx.x >> 6;
    const int t = blockIdx.x * 4 + wid, m = blockIdx.y;
    if (t >= NN) return;
    const int idx  = m * NN + t;
    const int row0 = __builtin_amdgcn_readfirstlane(rs[idx] + boff[idx >> 8]);
    const int deg  = __builtin_amdgcn_readfirstlane(counts[idx]);
    const int kl   = lane >> 3;
    const int l4   = lane * 4;

    const float erm  = er[(size_t)idx * NH + kl];
    const float* elm = el + (size_t)m * NN * NH;
    const u16*   fm  = feat + (size_t)m * NN * DF;
    const int*   cs  = src_csr + row0;

    float sm = 0.f;
    f32x2 A01; A01.x = 0.f; A01.y = 0.f;
    f32x2 A23; A23.x = 0.f; A23.y = 0.f;

    int j = 0;
    for (; j + 8 <= deg; j += 8) {
        int s[8];
#pragma unroll
        for (int q = 0; q < 8; q++) s[q] = __builtin_amdgcn_readfirstlane(cs[j + q]);
        float x[8];
#pragma unroll
        for (int q = 0; q < 8; q++) x[q] = elm[(size_t)s[q] * NH + kl];
        uint2 u[8];
#pragma unroll
        for (int q = 0; q < 8; q++) u[q] = *(const uint2*)(fm + (size_t)s[q] * DF + l4);
#pragma unroll
        for (int q = 0; q < 8; q++) {
            float tq = x[q] + erm;
            tq = fmaxf(tq, 0.2f * tq);
            float w = __expf(tq);
            sm += w;
            f32x2 wv; wv.x = w; wv.y = w;
            A01 += wv * bfp(u[q].x);
            A23 += wv * bfp(u[q].y);
        }
    }
    for (; j + 4 <= deg; j += 4) {
        int s[4];
#pragma unroll
        for (int q = 0; q < 4; q++) s[q] = __builtin_amdgcn_readfirstlane(cs[j + q]);
        float x[4];
#pragma unroll
        for (int q = 0; q < 4; q++) x[q] = elm[(size_t)s[q] * NH + kl];
        uint2 u[4];
#pragma unroll
        for (int q = 0; q < 4; q++) u[q] = *(const uint2*)(fm + (size_t)s[q] * DF + l4);
#pragma unroll
        for (int q = 0; q < 4; q++) {
            float tq = x[q] + erm;
            tq = fmaxf(tq, 0.2f * tq);
            float w = __expf(tq);
            sm += w;
            f32x2 wv; wv.x = w; wv.y = w;
            A01 += wv * bfp(u[q].x);
            A23 += wv * bfp(u[q].y);
        }
    }
    for (; j < deg; ++j) {
        int s0 = __builtin_amdgcn_readfirstlane(cs[j]);
        float x = elm[(size_t)s0 * NH + kl] + erm;
        x = fmaxf(x, 0.2f * x);
        float w = __expf(x);
        sm += w;
        uint2 u = *(const uint2*)(fm + (size_t)s0 * DF + l4);
        f32x2 wv; wv.x = w; wv.y = w;
        A01 += wv * bfp(u.x);
        A23 += wv * bfp(u.y);
    }
    const float rdm = 1.f / (sm + 1e-9f);

    float4 ub = *(const float4*)(bias + m * DF + l4);
    float z0 = A01.x * rdm + ub.x, z1 = A01.y * rdm + ub.y;
    float z2 = A23.x * rdm + ub.z, z3 = A23.y * rdm + ub.w;
    z0 = z0 > 0.f ? z0 : __expf(z0) - 1.f;
    z1 = z1 > 0.f ? z1 : __expf(z1) - 1.f;
    z2 = z2 > 0.f ? z2 : __expf(z2) - 1.f;
    z3 = z3 > 0.f ? z3 : __expf(z3) - 1.f;
    uint2 o;
    o.x = (u32)f2bf(z0) | ((u32)f2bf(z1) << 16);
    o.y = (u32)f2bf(z2) | ((u32)f2bf(z3) << 16);
    *(uint2*)(z + ((size_t)m * NN + t) * DF + l4) = o;
}

// ---------------------------------------------------------------------------
// 5) Semantic attention logits via MFMA, fused fast-tanh/w2/reduce epilogue.
// ---------------------------------------------------------------------------
__global__ __launch_bounds__(256) void k_sem(
    const u16* __restrict__ z, const u16* __restrict__ W1T,
    const float* __restrict__ b1, const float* __restrict__ w2,
    float* __restrict__ w_acc)
{
    __shared__ float buck[MP];
    const int tid = threadIdx.x, lane = tid & 63, wid = tid >> 6;
    const int quad = lane >> 4, l16 = lane & 15;
    if (tid < MP) buck[tid] = 0.f;
    __syncthreads();

    const int row0 = blockIdx.x * 64 + wid * 16;
    const int arow = row0 + l16;
    const int arc  = arow < NC ? arow : NC - 1;
    const u16* ab = z + (size_t)arc * DF + quad * 8;
    bf16x8 afrag[8];
#pragma unroll
    for (int ks = 0; ks < 8; ks++) afrag[ks] = *(const bf16x8*)(ab + ks * 32);

    const u16* bb0 = W1T + (size_t)l16 * DF + quad * 8;
    float rsum[4] = {0.f, 0.f, 0.f, 0.f};
#pragma unroll
    for (int nt = 0; nt < 8; nt++) {
        f32x4 acc; acc[0]=0.f; acc[1]=0.f; acc[2]=0.f; acc[3]=0.f;
        const u16* bb = bb0 + (size_t)nt * 16 * DF;
#pragma unroll
        for (int ks = 0; ks < 8; ks++) {
            bf16x8 bfrag = *(const bf16x8*)(bb + ks * 32);
            acc = __builtin_amdgcn_mfma_f32_16x16x32_bf16(afrag[ks], bfrag, acc, 0, 0, 0);
        }
        const int col = nt * 16 + l16;
        const float bb1 = b1[col], ww2 = w2[col];
#pragma unroll
        for (int r = 0; r < 4; r++) rsum[r] += tanh_fast(acc[r] + bb1) * ww2;
    }
#pragma unroll
    for (int msk = 1; msk <= 8; msk <<= 1)
#pragma unroll
        for (int r = 0; r < 4; r++) rsum[r] += __shfl_xor(rsum[r], msk);

    if (l16 == 0) {
#pragma unroll
        for (int r = 0; r < 4; r++) {
            int g = row0 + quad * 4 + r;
            if (g < NC) atomicAdd(&buck[g / NN], rsum[r]);
        }
    }
    __syncthreads();
    if (tid < MP) atomicAdd(w_acc + tid, buck[tid]);
}

__global__ void k_beta(const float* __restrict__ w_acc, float* __restrict__ beta) {
    if (threadIdx.x == 0 && blockIdx.x == 0) {
        float w0 = w_acc[0] / (float)NN, w1 = w_acc[1] / (float)NN, w2 = w_acc[2] / (float)NN;
        float mx = fmaxf(w0, fmaxf(w1, w2));
        float e0 = expf(w0 - mx), e1 = expf(w1 - mx), e2 = expf(w2 - mx);
        float s = e0 + e1 + e2;
        beta[0] = e0 / s; beta[1] = e1 / s; beta[2] = e2 / s;
    }
}

__global__ __launch_bounds__(256) void k_combine(
    const u16* __restrict__ z, const float* __restrict__ beta, float* __restrict__ out)
{
    size_t i = ((size_t)blockIdx.x * 256 + threadIdx.x) * 8;
    if (i >= (size_t)NN * DF) return;
    float b0 = beta[0], b1 = beta[1], b2 = beta[2];
    uint4 u0 = *(const uint4*)(z + i);
    uint4 u1 = *(const uint4*)(z + (size_t)NN * DF + i);
    uint4 u2 = *(const uint4*)(z + 2 * (size_t)NN * DF + i);
    float4 oa, ob;
    oa.x = b0 * bf2f((u16)(u0.x & 0xffff)) + b1 * bf2f((u16)(u1.x & 0xffff)) + b2 * bf2f((u16)(u2.x & 0xffff));
    oa.y = b0 * bf2f((u16)(u0.x >> 16))    + b1 * bf2f((u16)(u1.x >> 16))    + b2 * bf2f((u16)(u2.x >> 16));
    oa.z = b0 * bf2f((u16)(u0.y & 0xffff)) + b1 * bf2f((u16)(u1.y & 0xffff)) + b2 * bf2f((u16)(u2.y & 0xffff));
    oa.w = b0 * bf2f((u16)(u0.y >> 16))    + b1 * bf2f((u16)(u1.y >> 16))    + b2 * bf2f((u16)(u2.y >> 16));
    ob.x = b0 * bf2f((u16)(u0.z & 0xffff)) + b1 * bf2f((u16)(u1.z & 0xffff)) + b2 * bf2f((u16)(u2.z & 0xffff));
    ob.y = b0 * bf2f((u16)(u0.z >> 16))    + b1 * bf2f((u16)(u1.z >> 16))    + b2 * bf2f((u16)(u2.z >> 16));
    ob.z = b0 * bf2f((u16)(u0.w & 0xffff)) + b1 * bf2f((u16)(u1.w & 0xffff)) + b2 * bf2f((u16)(u2.w & 0xffff));
    ob.w = b0 * bf2f((u16)(u0.w >> 16))    + b1 * bf2f((u16)(u1.w >> 16))    + b2 * bf2f((u16)(u2.w >> 16));
    *(float4*)(out + i) = oa;
    *(float4*)(out + i + 4) = ob;
}

// ---------------------------------------------------------------------------
extern "C" void kernel_launch(void* const* d_in, const int* in_sizes, int n_in,
                              void* d_out, int out_size, void* d_ws, size_t ws_size,
                              hipStream_t stream)
{
    const float* h    = (const float*)d_in[0];
    const float* Wg   = (const float*)d_in[1];
    const float* al   = (const float*)d_in[2];
    const float* ar   = (const float*)d_in[3];
    const float* bias = (const float*)d_in[4];
    const float* W1   = (const float*)d_in[5];
    const float* b1   = (const float*)d_in[6];
    const float* w2   = (const float*)d_in[7];
    const int*   src  = (const int*)d_in[8];
    const int*   dst  = (const int*)d_in[9];
    float* out = (float*)d_out;

    char* w = (char*)d_ws;
    size_t off = 0;
    auto take = [&](size_t b) -> char* {
        char* p = w + off;
        off = (off + b + 255) & ~(size_t)255;
        return p;
    };
    u16*   feat    = (u16*)  take((size_t)MP * NN * DF * 2);
    u16*   zbuf    = (u16*)  take((size_t)MP * NN * DF * 2);
    u16*   hb      = (u16*)  take((size_t)NN * DIN * 2);
    u16*   WgT     = (u16*)  take((size_t)MP * DF * DIN * 2);
    u16*   W1T     = (u16*)  take((size_t)HID * DF * 2);
    u16*   WALT    = (u16*)  take((size_t)MP * 16 * DIN * 2);
    float* el      = (float*)take((size_t)MP * NN * NH * 4);
    float* er      = (float*)take((size_t)MP * NN * NH * 4);
    int*   counts  = (int*)  take((size_t)NC * 4);
    int*   rowst   = (int*)  take((size_t)NC * 4);
    int*   src_csr = (int*)  take((size_t)MP * NE * 4);
    int*   bsum    = (int*)  take(1024 * 4);
    int*   boff    = (int*)  take(1024 * 4);
    float* w_acc   = (float*)take(64);
    float* beta    = (float*)take(64);
    // rank is dead before k_node writes zbuf -> alias it onto zbuf
    int*   rank    = (int*)zbuf;

    hipMemsetAsync(counts, 0, (size_t)NC * 4, stream);
    hipMemsetAsync(w_acc, 0, 64, stream);

    k_cvt_count<<<CVT_NB + MP * CNT_NB, 256, 0, stream>>>(
        h, Wg, W1, al, ar, hb, WgT, W1T, WALT, dst, counts, rank);

    k_gemm_feat<<<dim3((NN + 63) / 64, MP), 256, 0, stream>>>(hb, WgT, WALT, feat, el, er);
    k_scan_a<<<SCAN_NB, 256, 0, stream>>>(counts, rowst, bsum);
    k_scan_b<<<1, 1024, 0, stream>>>(bsum, boff);
    k_scatter<<<dim3(CNT_NB, MP), 256, 0, stream>>>(src, dst, rowst, boff, rank, src_csr);
    k_node<<<dim3((NN + 3) / 4, MP), 256, 0, stream>>>(src_csr, rowst, boff, counts, el, er, feat, bias, zbuf);
    k_sem<<<(NC + 63) / 64, 256, 0, stream>>>(zbuf, W1T, b1, w2, w_acc);
    k_beta<<<1, 64, 0, stream>>>(w_acc, beta);
    k_combine<<<(NN * DF / 8 + 255) / 256, 256, 0, stream>>>(zbuf, beta, out);
}

// Round 2
// 670.330 us; speedup vs baseline: 1.0124x; 1.0015x over previous
//
#include <hip/hip_runtime.h>
#include <hip/hip_bf16.h>

#define NN   50000
#define NE   800000
#define MP   3
#define DIN  128
#define DF   256     // HEADS*OUT_DIM
#define NH   8
#define HID  128
#define NC   (MP*NN)              // 150000
#define SCAN_NB ((NC + 255)/256)  // 586

typedef unsigned short u16;
typedef unsigned int   u32;
typedef __attribute__((ext_vector_type(8))) short bf16x8;   // MFMA A/B frag
typedef __attribute__((ext_vector_type(4))) float f32x4;    // MFMA C/D frag
typedef __attribute__((ext_vector_type(2))) float f32x2;    // pk-math pair

__device__ __forceinline__ float bf2f(u16 u) {
    return __uint_as_float(((u32)u) << 16);
}
__device__ __forceinline__ u16 f2bf(float f) {
    u32 x = __float_as_uint(f);
    u32 r = x + 0x7fffu + ((x >> 16) & 1u);   // round-to-nearest-even
    return (u16)(r >> 16);
}
__device__ __forceinline__ f32x2 bfp(u32 u) {   // unpack bf16 pair -> f32x2
    f32x2 r;
    r.x = __uint_as_float(u << 16);
    r.y = __uint_as_float(u & 0xffff0000u);
    return r;
}
__device__ __forceinline__ float tanh_fast(float x) {
    float c = fminf(fmaxf(x, -15.f), 15.f);
    float t = __expf(2.f * c);
    return (t - 1.f) / (t + 1.f);
}

// ---------------------------------------------------------------------------
// 0) fused: converts (h->hb, Wg->WgT, W1->W1T, WAL) + edge count w/ rank.
//    cvt blocks [0, CVT_NB); count blocks [CVT_NB, CVT_NB + 3*CNT_NB).
// ---------------------------------------------------------------------------
#define CVT_H_N   (NN * DIN / 8)          // 800000
#define CVT_WG_N  (MP * DF * DIN)         // 98304
#define CVT_W1_N  (HID * DF)              // 32768
#define CVT_WAL_N (MP * 16 * DIN)         // 6144
#define CVT_TOT_N (CVT_H_N + CVT_WG_N + CVT_W1_N + CVT_WAL_N)   // 937216
#define CVT_NB    ((CVT_TOT_N + 255) / 256)                     // 3661
#define CNT_NB    ((NE + 255) / 256)                            // 3125
__global__ __launch_bounds__(256) void k_cvt_count(
    const float* __restrict__ h, const float* __restrict__ Wg, const float* __restrict__ W1,
    const float* __restrict__ al, const float* __restrict__ ar,
    u16* __restrict__ hb, u16* __restrict__ WgT, u16* __restrict__ W1T, u16* __restrict__ WALT,
    const int* __restrict__ dst, int* __restrict__ counts, int* __restrict__ rank)
{
    if (blockIdx.x >= CVT_NB) {           // edge-count path
        int b = blockIdx.x - CVT_NB;
        int m = b / CNT_NB;
        int e = (b - m * CNT_NB) * 256 + threadIdx.x;
        if (e < NE) {
            int idx = m * NN + dst[(size_t)m * NE + e];
            rank[(size_t)m * NE + e] = atomicAdd(&counts[idx], 1);
        }
        return;
    }
    int gid = blockIdx.x * 256 + threadIdx.x;
    if (gid < CVT_H_N) {
        size_t i8 = (size_t)gid * 8;
        float4 a = *(const float4*)(h + i8);
        float4 b = *(const float4*)(h + i8 + 4);
        uint4 o;
        o.x = (u32)f2bf(a.x) | ((u32)f2bf(a.y) << 16);
        o.y = (u32)f2bf(a.z) | ((u32)f2bf(a.w) << 16);
        o.z = (u32)f2bf(b.x) | ((u32)f2bf(b.y) << 16);
        o.w = (u32)f2bf(b.z) | ((u32)f2bf(b.w) << 16);
        *(uint4*)(hb + i8) = o;
    } else if (gid < CVT_H_N + CVT_WG_N) {
        int g = gid - CVT_H_N;
        int k = g % DIN, n = (g / DIN) % DF, m = g / (DIN * DF);
        WgT[g] = f2bf(Wg[((size_t)m * DIN + k) * DF + n]);
    } else if (gid < CVT_H_N + CVT_WG_N + CVT_W1_N) {
        int g = gid - CVT_H_N - CVT_WG_N;
        int k = g % DF, n = g / DF;
        W1T[g] = f2bf(W1[(size_t)k * HID + n]);
    } else if (gid < CVT_TOT_N) {
        int g = gid - CVT_H_N - CVT_WG_N - CVT_W1_N;
        int k = g & (DIN - 1), c = (g >> 7) & 15, m = g >> 11;
        int hh = c & 7;
        const float* a  = (c < 8 ? al : ar) + ((size_t)m * NH + hh) * 32;
        const float* wg = Wg + ((size_t)m * DIN + k) * DF + 32 * hh;
        float s = 0.f;
#pragma unroll
        for (int d = 0; d < 32; d++) s += wg[d] * a[d];
        WALT[g] = f2bf(s);
    }
}

// ---------------------------------------------------------------------------
// 1) feat[m] = h @ W_gat[m] via MFMA 16x16x32 bf16; wave does 16x256 strip,
//    plus one extra col-block vs WALT producing el/er (fp32) in the epilogue.
// ---------------------------------------------------------------------------
__global__ __launch_bounds__(256) void k_gemm_feat(
    const u16* __restrict__ hb, const u16* __restrict__ WgT, const u16* __restrict__ WALT,
    u16* __restrict__ feat, float* __restrict__ el, float* __restrict__ er)
{
    const int tid = threadIdx.x, lane = tid & 63, wid = tid >> 6;
    const int quad = lane >> 4, l16 = lane & 15;
    const int m    = blockIdx.y;
    const int row0 = blockIdx.x * 64 + wid * 16;

    const int arow = row0 + l16;
    const int arc  = arow < NN ? arow : NN - 1;
    const u16* ab = hb + (size_t)arc * DIN + quad * 8;
    bf16x8 afrag[4];
#pragma unroll
    for (int ks = 0; ks < 4; ks++) afrag[ks] = *(const bf16x8*)(ab + ks * 32);

    const u16* bb0 = WgT + ((size_t)m * DF + l16) * DIN + quad * 8;
    f32x4 acc[16];
#pragma unroll
    for (int nt = 0; nt < 16; nt++) { acc[nt][0]=0.f; acc[nt][1]=0.f; acc[nt][2]=0.f; acc[nt][3]=0.f; }

#pragma unroll
    for (int nt = 0; nt < 16; nt++) {
        const u16* bb = bb0 + (size_t)nt * 16 * DIN;
#pragma unroll
        for (int ks = 0; ks < 4; ks++) {
            bf16x8 bfrag = *(const bf16x8*)(bb + ks * 32);
            acc[nt] = __builtin_amdgcn_mfma_f32_16x16x32_bf16(afrag[ks], bfrag, acc[nt], 0, 0, 0);
        }
    }
    // extra col-block: el/er
    f32x4 acce; acce[0]=0.f; acce[1]=0.f; acce[2]=0.f; acce[3]=0.f;
    {
        const u16* eb = WALT + ((size_t)m * 16 + l16) * DIN + quad * 8;
#pragma unroll
        for (int ks = 0; ks < 4; ks++) {
            bf16x8 bfrag = *(const bf16x8*)(eb + ks * 32);
            acce = __builtin_amdgcn_mfma_f32_16x16x32_bf16(afrag[ks], bfrag, acce, 0, 0, 0);
        }
    }
    const int rbase = row0 + quad * 4;
#pragma unroll
    for (int nt = 0; nt < 16; nt++)
#pragma unroll
        for (int r = 0; r < 4; r++) {
            int gr = rbase + r;
            if (gr < NN)
                feat[((size_t)m * NN + gr) * DF + nt * 16 + l16] = f2bf(acc[nt][r]);
        }
#pragma unroll
    for (int r = 0; r < 4; r++) {
        int gr = rbase + r;
        if (gr < NN) {
            if (l16 < 8) el[((size_t)m * NN + gr) * NH + l16]       = acce[r];
            else         er[((size_t)m * NN + gr) * NH + (l16 - 8)] = acce[r];
        }
    }
}

// ---------------------------------------------------------------------------
// 3) scan (2 kernels; boff add folded into consumers) + rank-based scatter.
// ---------------------------------------------------------------------------
__global__ void k_scan_a(const int* __restrict__ counts, int* __restrict__ rs, int* __restrict__ bsum) {
    __shared__ int s[256];
    int tid = threadIdx.x, g = blockIdx.x * 256 + tid;
    int v = (g < NC) ? counts[g] : 0;
    s[tid] = v; __syncthreads();
    for (int off = 1; off < 256; off <<= 1) {
        int u = (tid >= off) ? s[tid - off] : 0;
        __syncthreads();
        s[tid] += u;
        __syncthreads();
    }
    if (g < NC) rs[g] = s[tid] - v;
    if (tid == 255) bsum[blockIdx.x] = s[255];
}

__global__ void k_scan_b(const int* __restrict__ bsum, int* __restrict__ boff) {
    __shared__ int s[1024];
    int tid = threadIdx.x;
    int v = (tid < SCAN_NB) ? bsum[tid] : 0;
    s[tid] = v; __syncthreads();
    for (int off = 1; off < 1024; off <<= 1) {
        int u = (tid >= off) ? s[tid - off] : 0;
        __syncthreads();
        s[tid] += u;
        __syncthreads();
    }
    if (tid < SCAN_NB) boff[tid] = s[tid] - v;
}

__global__ void k_scatter(const int* __restrict__ src, const int* __restrict__ dst,
                          const int* __restrict__ rs, const int* __restrict__ boff,
                          const int* __restrict__ rank, int* __restrict__ src_csr) {
    int e = blockIdx.x * 256 + threadIdx.x, m = blockIdx.y;
    if (e >= NE) return;
    int idx = m * NN + dst[(size_t)m * NE + e];
    int pos = rs[idx] + boff[idx >> 8] + rank[(size_t)m * NE + e];
    src_csr[pos] = src[(size_t)m * NE + e];
}

// ---------------------------------------------------------------------------
// 4) Destination-centric GAT. Wave-uniform CSR walk in SGPRs (readfirstlane).
//    NEW: two independent destination nodes per wave -> two independent scalar
//    chains and up to 16 feat-gathers in flight (latency-bound fix).
// ---------------------------------------------------------------------------
__device__ __forceinline__ void edge_body(float x, float erm, float& sm,
                                          f32x2& A01, f32x2& A23, uint2 u)
{
    float tq = x + erm;
    tq = fmaxf(tq, 0.2f * tq);
    float w = __expf(tq);
    sm += w;
    f32x2 wv; wv.x = w; wv.y = w;
    A01 += wv * bfp(u.x);
    A23 += wv * bfp(u.y);
}

__device__ __forceinline__ void drain_csr(const int* cs, int j, int deg,
                                          const float* elm, const u16* fm,
                                          int kl, int l4, float erm,
                                          float& sm, f32x2& A01, f32x2& A23)
{
    for (; j + 8 <= deg; j += 8) {
        int s[8];
#pragma unroll
        for (int q = 0; q < 8; q++) s[q] = __builtin_amdgcn_readfirstlane(cs[j + q]);
        float x[8];
#pragma unroll
        for (int q = 0; q < 8; q++) x[q] = elm[(size_t)s[q] * NH + kl];
        uint2 u[8];
#pragma unroll
        for (int q = 0; q < 8; q++) u[q] = *(const uint2*)(fm + (size_t)s[q] * DF + l4);
#pragma unroll
        for (int q = 0; q < 8; q++) edge_body(x[q], erm, sm, A01, A23, u[q]);
    }
    for (; j + 4 <= deg; j += 4) {
        int s[4];
#pragma unroll
        for (int q = 0; q < 4; q++) s[q] = __builtin_amdgcn_readfirstlane(cs[j + q]);
        float x[4];
#pragma unroll
        for (int q = 0; q < 4; q++) x[q] = elm[(size_t)s[q] * NH + kl];
        uint2 u[4];
#pragma unroll
        for (int q = 0; q < 4; q++) u[q] = *(const uint2*)(fm + (size_t)s[q] * DF + l4);
#pragma unroll
        for (int q = 0; q < 4; q++) edge_body(x[q], erm, sm, A01, A23, u[q]);
    }
    for (; j < deg; ++j) {
        int s0 = __builtin_amdgcn_readfirstlane(cs[j]);
        float x = elm[(size_t)s0 * NH + kl];
        uint2 u = *(const uint2*)(fm + (size_t)s0 * DF + l4);
        edge_body(x, erm, sm, A01, A23, u);
    }
}

__global__ __launch_bounds__(256) void k_node(
    const int* __restrict__ src_csr, const int* __restrict__ rs, const int* __restrict__ boff,
    const int* __restrict__ counts,
    const float* __restrict__ el, const float* __restrict__ er,
    const u16* __restrict__ feat, const float* __restrict__ bias, u16* __restrict__ z)
{
    const int lane = threadIdx.x & 63, wid = threadIdx.x >> 6;
    const int t0 = blockIdx.x * 8 + wid * 2, m = blockIdx.y;
    if (t0 >= NN) return;
    const int t1 = t0 + 1;                       // NN even, grid exact -> t1 < NN
    const int idx0 = m * NN + t0, idx1 = m * NN + t1;
    const int row0 = __builtin_amdgcn_readfirstlane(rs[idx0] + boff[idx0 >> 8]);
    const int deg0 = __builtin_amdgcn_readfirstlane(counts[idx0]);
    const int row1 = __builtin_amdgcn_readfirstlane(rs[idx1] + boff[idx1 >> 8]);
    const int deg1 = __builtin_amdgcn_readfirstlane(counts[idx1]);
    const int kl   = lane >> 3;
    const int l4   = lane * 4;

    const float erm0 = er[(size_t)idx0 * NH + kl];
    const float erm1 = er[(size_t)idx1 * NH + kl];
    const float* elm = el + (size_t)m * NN * NH;
    const u16*   fm  = feat + (size_t)m * NN * DF;
    const int*   cs0 = src_csr + row0;
    const int*   cs1 = src_csr + row1;

    float sm0 = 0.f, sm1 = 0.f;
    f32x2 A01_0; A01_0.x = 0.f; A01_0.y = 0.f;
    f32x2 A23_0; A23_0.x = 0.f; A23_0.y = 0.f;
    f32x2 A01_1; A01_1.x = 0.f; A01_1.y = 0.f;
    f32x2 A23_1; A23_1.x = 0.f; A23_1.y = 0.f;

    int j0 = 0, j1 = 0;
    // interleaved 8+8 tier: two independent scalar chains, 16 gathers in flight
    while (j0 + 8 <= deg0 && j1 + 8 <= deg1) {
        int s0[8], s1[8];
#pragma unroll
        for (int q = 0; q < 8; q++) s0[q] = __builtin_amdgcn_readfirstlane(cs0[j0 + q]);
#pragma unroll
        for (int q = 0; q < 8; q++) s1[q] = __builtin_amdgcn_readfirstlane(cs1[j1 + q]);
        float x0[8], x1[8];
#pragma unroll
        for (int q = 0; q < 8; q++) x0[q] = elm[(size_t)s0[q] * NH + kl];
#pragma unroll
        for (int q = 0; q < 8; q++) x1[q] = elm[(size_t)s1[q] * NH + kl];
        uint2 u0[8], u1[8];
#pragma unroll
        for (int q = 0; q < 8; q++) u0[q] = *(const uint2*)(fm + (size_t)s0[q] * DF + l4);
#pragma unroll
        for (int q = 0; q < 8; q++) u1[q] = *(const uint2*)(fm + (size_t)s1[q] * DF + l4);
#pragma unroll
        for (int q = 0; q < 8; q++) edge_body(x0[q], erm0, sm0, A01_0, A23_0, u0[q]);
#pragma unroll
        for (int q = 0; q < 8; q++) edge_body(x1[q], erm1, sm1, A01_1, A23_1, u1[q]);
        j0 += 8; j1 += 8;
    }
    // interleaved 4+4 tier
    while (j0 + 4 <= deg0 && j1 + 4 <= deg1) {
        int s0[4], s1[4];
#pragma unroll
        for (int q = 0; q < 4; q++) s0[q] = __builtin_amdgcn_readfirstlane(cs0[j0 + q]);
#pragma unroll
        for (int q = 0; q < 4; q++) s1[q] = __builtin_amdgcn_readfirstlane(cs1[j1 + q]);
        float x0[4], x1[4];
#pragma unroll
        for (int q = 0; q < 4; q++) x0[q] = elm[(size_t)s0[q] * NH + kl];
#pragma unroll
        for (int q = 0; q < 4; q++) x1[q] = elm[(size_t)s1[q] * NH + kl];
        uint2 u0[4], u1[4];
#pragma unroll
        for (int q = 0; q < 4; q++) u0[q] = *(const uint2*)(fm + (size_t)s0[q] * DF + l4);
#pragma unroll
        for (int q = 0; q < 4; q++) u1[q] = *(const uint2*)(fm + (size_t)s1[q] * DF + l4);
#pragma unroll
        for (int q = 0; q < 4; q++) edge_body(x0[q], erm0, sm0, A01_0, A23_0, u0[q]);
#pragma unroll
        for (int q = 0; q < 4; q++) edge_body(x1[q], erm1, sm1, A01_1, A23_1, u1[q]);
        j0 += 4; j1 += 4;
    }
    // per-stream drains
    drain_csr(cs0, j0, deg0, elm, fm, kl, l4, erm0, sm0, A01_0, A23_0);
    drain_csr(cs1, j1, deg1, elm, fm, kl, l4, erm1, sm1, A01_1, A23_1);

    const float rdm0 = 1.f / (sm0 + 1e-9f);
    const float rdm1 = 1.f / (sm1 + 1e-9f);
    float4 ub = *(const float4*)(bias + m * DF + l4);

    {
        float z0 = A01_0.x * rdm0 + ub.x, z1 = A01_0.y * rdm0 + ub.y;
        float z2 = A23_0.x * rdm0 + ub.z, z3 = A23_0.y * rdm0 + ub.w;
        z0 = z0 > 0.f ? z0 : __expf(z0) - 1.f;
        z1 = z1 > 0.f ? z1 : __expf(z1) - 1.f;
        z2 = z2 > 0.f ? z2 : __expf(z2) - 1.f;
        z3 = z3 > 0.f ? z3 : __expf(z3) - 1.f;
        uint2 o;
        o.x = (u32)f2bf(z0) | ((u32)f2bf(z1) << 16);
        o.y = (u32)f2bf(z2) | ((u32)f2bf(z3) << 16);
        *(uint2*)(z + ((size_t)m * NN + t0) * DF + l4) = o;
    }
    {
        float z0 = A01_1.x * rdm1 + ub.x, z1 = A01_1.y * rdm1 + ub.y;
        float z2 = A23_1.x * rdm1 + ub.z, z3 = A23_1.y * rdm1 + ub.w;
        z0 = z0 > 0.f ? z0 : __expf(z0) - 1.f;
        z1 = z1 > 0.f ? z1 : __expf(z1) - 1.f;
        z2 = z2 > 0.f ? z2 : __expf(z2) - 1.f;
        z3 = z3 > 0.f ? z3 : __expf(z3) - 1.f;
        uint2 o;
        o.x = (u32)f2bf(z0) | ((u32)f2bf(z1) << 16);
        o.y = (u32)f2bf(z2) | ((u32)f2bf(z3) << 16);
        *(uint2*)(z + ((size_t)m * NN + t1) * DF + l4) = o;
    }
}

// ---------------------------------------------------------------------------
// 5) Semantic attention logits via MFMA, fused fast-tanh/w2/reduce epilogue.
// ---------------------------------------------------------------------------
__global__ __launch_bounds__(256) void k_sem(
    const u16* __restrict__ z, const u16* __restrict__ W1T,
    const float* __restrict__ b1, const float* __restrict__ w2,
    float* __restrict__ w_acc)
{
    __shared__ float buck[MP];
    const int tid = threadIdx.x, lane = tid & 63, wid = tid >> 6;
    const int quad = lane >> 4, l16 = lane & 15;
    if (tid < MP) buck[tid] = 0.f;
    __syncthreads();

    const int row0 = blockIdx.x * 64 + wid * 16;
    const int arow = row0 + l16;
    const int arc  = arow < NC ? arow : NC - 1;
    const u16* ab = z + (size_t)arc * DF + quad * 8;
    bf16x8 afrag[8];
#pragma unroll
    for (int ks = 0; ks < 8; ks++) afrag[ks] = *(const bf16x8*)(ab + ks * 32);

    const u16* bb0 = W1T + (size_t)l16 * DF + quad * 8;
    float rsum[4] = {0.f, 0.f, 0.f, 0.f};
#pragma unroll
    for (int nt = 0; nt < 8; nt++) {
        f32x4 acc; acc[0]=0.f; acc[1]=0.f; acc[2]=0.f; acc[3]=0.f;
        const u16* bb = bb0 + (size_t)nt * 16 * DF;
#pragma unroll
        for (int ks = 0; ks < 8; ks++) {
            bf16x8 bfrag = *(const bf16x8*)(bb + ks * 32);
            acc = __builtin_amdgcn_mfma_f32_16x16x32_bf16(afrag[ks], bfrag, acc, 0, 0, 0);
        }
        const int col = nt * 16 + l16;
        const float bb1 = b1[col], ww2 = w2[col];
#pragma unroll
        for (int r = 0; r < 4; r++) rsum[r] += tanh_fast(acc[r] + bb1) * ww2;
    }
#pragma unroll
    for (int msk = 1; msk <= 8; msk <<= 1)
#pragma unroll
        for (int r = 0; r < 4; r++) rsum[r] += __shfl_xor(rsum[r], msk);

    if (l16 == 0) {
#pragma unroll
        for (int r = 0; r < 4; r++) {
            int g = row0 + quad * 4 + r;
            if (g < NC) atomicAdd(&buck[g / NN], rsum[r]);
        }
    }
    __syncthreads();
    if (tid < MP) atomicAdd(w_acc + tid, buck[tid]);
}

__global__ void k_beta(const float* __restrict__ w_acc, float* __restrict__ beta) {
    if (threadIdx.x == 0 && blockIdx.x == 0) {
        float w0 = w_acc[0] / (float)NN, w1 = w_acc[1] / (float)NN, w2 = w_acc[2] / (float)NN;
        float mx = fmaxf(w0, fmaxf(w1, w2));
        float e0 = expf(w0 - mx), e1 = expf(w1 - mx), e2 = expf(w2 - mx);
        float s = e0 + e1 + e2;
        beta[0] = e0 / s; beta[1] = e1 / s; beta[2] = e2 / s;
    }
}

__global__ __launch_bounds__(256) void k_combine(
    const u16* __restrict__ z, const float* __restrict__ beta, float* __restrict__ out)
{
    size_t i = ((size_t)blockIdx.x * 256 + threadIdx.x) * 8;
    if (i >= (size_t)NN * DF) return;
    float b0 = beta[0], b1 = beta[1], b2 = beta[2];
    uint4 u0 = *(const uint4*)(z + i);
    uint4 u1 = *(const uint4*)(z + (size_t)NN * DF + i);
    uint4 u2 = *(const uint4*)(z + 2 * (size_t)NN * DF + i);
    float4 oa, ob;
    oa.x = b0 * bf2f((u16)(u0.x & 0xffff)) + b1 * bf2f((u16)(u1.x & 0xffff)) + b2 * bf2f((u16)(u2.x & 0xffff));
    oa.y = b0 * bf2f((u16)(u0.x >> 16))    + b1 * bf2f((u16)(u1.x >> 16))    + b2 * bf2f((u16)(u2.x >> 16));
    oa.z = b0 * bf2f((u16)(u0.y & 0xffff)) + b1 * bf2f((u16)(u1.y & 0xffff)) + b2 * bf2f((u16)(u2.y & 0xffff));
    oa.w = b0 * bf2f((u16)(u0.y >> 16))    + b1 * bf2f((u16)(u1.y >> 16))    + b2 * bf2f((u16)(u2.y >> 16));
    ob.x = b0 * bf2f((u16)(u0.z & 0xffff)) + b1 * bf2f((u16)(u1.z & 0xffff)) + b2 * bf2f((u16)(u2.z & 0xffff));
    ob.y = b0 * bf2f((u16)(u0.z >> 16))    + b1 * bf2f((u16)(u1.z >> 16))    + b2 * bf2f((u16)(u2.z >> 16));
    ob.z = b0 * bf2f((u16)(u0.w & 0xffff)) + b1 * bf2f((u16)(u1.w & 0xffff)) + b2 * bf2f((u16)(u2.w & 0xffff));
    ob.w = b0 * bf2f((u16)(u0.w >> 16))    + b1 * bf2f((u16)(u1.w >> 16))    + b2 * bf2f((u16)(u2.w >> 16));
    *(float4*)(out + i) = oa;
    *(float4*)(out + i + 4) = ob;
}

// ---------------------------------------------------------------------------
extern "C" void kernel_launch(void* const* d_in, const int* in_sizes, int n_in,
                              void* d_out, int out_size, void* d_ws, size_t ws_size,
                              hipStream_t stream)
{
    const float* h    = (const float*)d_in[0];
    const float* Wg   = (const float*)d_in[1];
    const float* al   = (const float*)d_in[2];
    const float* ar   = (const float*)d_in[3];
    const float* bias = (const float*)d_in[4];
    const float* W1   = (const float*)d_in[5];
    const float* b1   = (const float*)d_in[6];
    const float* w2   = (const float*)d_in[7];
    const int*   src  = (const int*)d_in[8];
    const int*   dst  = (const int*)d_in[9];
    float* out = (float*)d_out;

    char* w = (char*)d_ws;
    size_t off = 0;
    auto take = [&](size_t b) -> char* {
        char* p = w + off;
        off = (off + b + 255) & ~(size_t)255;
        return p;
    };
    u16*   feat    = (u16*)  take((size_t)MP * NN * DF * 2);
    u16*   zbuf    = (u16*)  take((size_t)MP * NN * DF * 2);
    u16*   hb      = (u16*)  take((size_t)NN * DIN * 2);
    u16*   WgT     = (u16*)  take((size_t)MP * DF * DIN * 2);
    u16*   W1T     = (u16*)  take((size_t)HID * DF * 2);
    u16*   WALT    = (u16*)  take((size_t)MP * 16 * DIN * 2);
    float* el      = (float*)take((size_t)MP * NN * NH * 4);
    float* er      = (float*)take((size_t)MP * NN * NH * 4);
    int*   counts  = (int*)  take((size_t)NC * 4);
    int*   rowst   = (int*)  take((size_t)NC * 4);
    int*   src_csr = (int*)  take((size_t)MP * NE * 4);
    int*   bsum    = (int*)  take(1024 * 4);
    int*   boff    = (int*)  take(1024 * 4);
    float* w_acc   = (float*)take(64);
    float* beta    = (float*)take(64);
    // rank is dead before k_node writes zbuf -> alias it onto zbuf
    int*   rank    = (int*)zbuf;

    hipMemsetAsync(counts, 0, (size_t)NC * 4, stream);
    hipMemsetAsync(w_acc, 0, 64, stream);

    k_cvt_count<<<CVT_NB + MP * CNT_NB, 256, 0, stream>>>(
        h, Wg, W1, al, ar, hb, WgT, W1T, WALT, dst, counts, rank);

    k_gemm_feat<<<dim3((NN + 63) / 64, MP), 256, 0, stream>>>(hb, WgT, WALT, feat, el, er);
    k_scan_a<<<SCAN_NB, 256, 0, stream>>>(counts, rowst, bsum);
    k_scan_b<<<1, 1024, 0, stream>>>(bsum, boff);
    k_scatter<<<dim3(CNT_NB, MP), 256, 0, stream>>>(src, dst, rowst, boff, rank, src_csr);
    k_node<<<dim3((NN + 7) / 8, MP), 256, 0, stream>>>(src_csr, rowst, boff, counts, el, er, feat, bias, zbuf);
    k_sem<<<(NC + 63) / 64, 256, 0, stream>>>(zbuf, W1T, b1, w2, w_acc);
    k_beta<<<1, 64, 0, stream>>>(w_acc, beta);
    k_combine<<<(NN * DF / 8 + 255) / 256, 256, 0, stream>>>(zbuf, beta, out);
}

// Round 3
// 666.550 us; speedup vs baseline: 1.0181x; 1.0057x over previous
//
#include <hip/hip_runtime.h>
#include <hip/hip_bf16.h>

#define NN   50000
#define NE   800000
#define MP   3
#define DIN  128
#define DF   256     // HEADS*OUT_DIM
#define NH   8
#define HID  128
#define NC   (MP*NN)              // 150000
#define SCAN_NB ((NC + 255)/256)  // 586

typedef unsigned short u16;
typedef unsigned int   u32;
typedef __attribute__((ext_vector_type(8))) short bf16x8;   // MFMA A/B frag
typedef __attribute__((ext_vector_type(4))) float f32x4;    // MFMA C/D frag
typedef __attribute__((ext_vector_type(2))) float f32x2;    // pk-math pair

__device__ __forceinline__ float bf2f(u16 u) {
    return __uint_as_float(((u32)u) << 16);
}
__device__ __forceinline__ u16 f2bf(float f) {
    u32 x = __float_as_uint(f);
    u32 r = x + 0x7fffu + ((x >> 16) & 1u);   // round-to-nearest-even
    return (u16)(r >> 16);
}
__device__ __forceinline__ f32x2 bfp(u32 u) {   // unpack bf16 pair -> f32x2
    f32x2 r;
    r.x = __uint_as_float(u << 16);
    r.y = __uint_as_float(u & 0xffff0000u);
    return r;
}
__device__ __forceinline__ float tanh_fast(float x) {
    float c = fminf(fmaxf(x, -15.f), 15.f);
    float t = __expf(2.f * c);
    return (t - 1.f) / (t + 1.f);
}

// ---------------------------------------------------------------------------
// 0) fused: converts (h->hb, Wg->WgT, W1->W1T, WAL) + edge count w/ rank.
//    cvt blocks [0, CVT_NB); count blocks [CVT_NB, CVT_NB + 3*CNT_NB).
// ---------------------------------------------------------------------------
#define CVT_H_N   (NN * DIN / 8)          // 800000
#define CVT_WG_N  (MP * DF * DIN)         // 98304
#define CVT_W1_N  (HID * DF)              // 32768
#define CVT_WAL_N (MP * 16 * DIN)         // 6144
#define CVT_TOT_N (CVT_H_N + CVT_WG_N + CVT_W1_N + CVT_WAL_N)   // 937216
#define CVT_NB    ((CVT_TOT_N + 255) / 256)                     // 3661
#define CNT_NB    ((NE + 255) / 256)                            // 3125
__global__ __launch_bounds__(256) void k_cvt_count(
    const float* __restrict__ h, const float* __restrict__ Wg, const float* __restrict__ W1,
    const float* __restrict__ al, const float* __restrict__ ar,
    u16* __restrict__ hb, u16* __restrict__ WgT, u16* __restrict__ W1T, u16* __restrict__ WALT,
    const int* __restrict__ dst, int* __restrict__ counts, int* __restrict__ rank)
{
    if (blockIdx.x >= CVT_NB) {           // edge-count path
        int b = blockIdx.x - CVT_NB;
        int m = b / CNT_NB;
        int e = (b - m * CNT_NB) * 256 + threadIdx.x;
        if (e < NE) {
            int idx = m * NN + dst[(size_t)m * NE + e];
            rank[(size_t)m * NE + e] = atomicAdd(&counts[idx], 1);
        }
        return;
    }
    int gid = blockIdx.x * 256 + threadIdx.x;
    if (gid < CVT_H_N) {
        size_t i8 = (size_t)gid * 8;
        float4 a = *(const float4*)(h + i8);
        float4 b = *(const float4*)(h + i8 + 4);
        uint4 o;
        o.x = (u32)f2bf(a.x) | ((u32)f2bf(a.y) << 16);
        o.y = (u32)f2bf(a.z) | ((u32)f2bf(a.w) << 16);
        o.z = (u32)f2bf(b.x) | ((u32)f2bf(b.y) << 16);
        o.w = (u32)f2bf(b.z) | ((u32)f2bf(b.w) << 16);
        *(uint4*)(hb + i8) = o;
    } else if (gid < CVT_H_N + CVT_WG_N) {
        int g = gid - CVT_H_N;
        int k = g % DIN, n = (g / DIN) % DF, m = g / (DIN * DF);
        WgT[g] = f2bf(Wg[((size_t)m * DIN + k) * DF + n]);
    } else if (gid < CVT_H_N + CVT_WG_N + CVT_W1_N) {
        int g = gid - CVT_H_N - CVT_WG_N;
        int k = g % DF, n = g / DF;
        W1T[g] = f2bf(W1[(size_t)k * HID + n]);
    } else if (gid < CVT_TOT_N) {
        int g = gid - CVT_H_N - CVT_WG_N - CVT_W1_N;
        int k = g & (DIN - 1), c = (g >> 7) & 15, m = g >> 11;
        int hh = c & 7;
        const float* a  = (c < 8 ? al : ar) + ((size_t)m * NH + hh) * 32;
        const float* wg = Wg + ((size_t)m * DIN + k) * DF + 32 * hh;
        float s = 0.f;
#pragma unroll
        for (int d = 0; d < 32; d++) s += wg[d] * a[d];
        WALT[g] = f2bf(s);
    }
}

// ---------------------------------------------------------------------------
// 1) feat[m] = h @ W_gat[m] via MFMA 16x16x32 bf16; wave does 16x256 strip,
//    plus one extra col-block vs WALT producing el/er (fp32) in the epilogue.
// ---------------------------------------------------------------------------
__global__ __launch_bounds__(256) void k_gemm_feat(
    const u16* __restrict__ hb, const u16* __restrict__ WgT, const u16* __restrict__ WALT,
    u16* __restrict__ feat, float* __restrict__ el, float* __restrict__ er)
{
    const int tid = threadIdx.x, lane = tid & 63, wid = tid >> 6;
    const int quad = lane >> 4, l16 = lane & 15;
    const int m    = blockIdx.y;
    const int row0 = blockIdx.x * 64 + wid * 16;

    const int arow = row0 + l16;
    const int arc  = arow < NN ? arow : NN - 1;
    const u16* ab = hb + (size_t)arc * DIN + quad * 8;
    bf16x8 afrag[4];
#pragma unroll
    for (int ks = 0; ks < 4; ks++) afrag[ks] = *(const bf16x8*)(ab + ks * 32);

    const u16* bb0 = WgT + ((size_t)m * DF + l16) * DIN + quad * 8;
    f32x4 acc[16];
#pragma unroll
    for (int nt = 0; nt < 16; nt++) { acc[nt][0]=0.f; acc[nt][1]=0.f; acc[nt][2]=0.f; acc[nt][3]=0.f; }

#pragma unroll
    for (int nt = 0; nt < 16; nt++) {
        const u16* bb = bb0 + (size_t)nt * 16 * DIN;
#pragma unroll
        for (int ks = 0; ks < 4; ks++) {
            bf16x8 bfrag = *(const bf16x8*)(bb + ks * 32);
            acc[nt] = __builtin_amdgcn_mfma_f32_16x16x32_bf16(afrag[ks], bfrag, acc[nt], 0, 0, 0);
        }
    }
    // extra col-block: el/er
    f32x4 acce; acce[0]=0.f; acce[1]=0.f; acce[2]=0.f; acce[3]=0.f;
    {
        const u16* eb = WALT + ((size_t)m * 16 + l16) * DIN + quad * 8;
#pragma unroll
        for (int ks = 0; ks < 4; ks++) {
            bf16x8 bfrag = *(const bf16x8*)(eb + ks * 32);
            acce = __builtin_amdgcn_mfma_f32_16x16x32_bf16(afrag[ks], bfrag, acce, 0, 0, 0);
        }
    }
    const int rbase = row0 + quad * 4;
#pragma unroll
    for (int nt = 0; nt < 16; nt++)
#pragma unroll
        for (int r = 0; r < 4; r++) {
            int gr = rbase + r;
            if (gr < NN)
                feat[((size_t)m * NN + gr) * DF + nt * 16 + l16] = f2bf(acc[nt][r]);
        }
#pragma unroll
    for (int r = 0; r < 4; r++) {
        int gr = rbase + r;
        if (gr < NN) {
            if (l16 < 8) el[((size_t)m * NN + gr) * NH + l16]       = acce[r];
            else         er[((size_t)m * NN + gr) * NH + (l16 - 8)] = acce[r];
        }
    }
}

// ---------------------------------------------------------------------------
// 3) scan (2 kernels; boff add folded into consumers) + rank-based scatter.
// ---------------------------------------------------------------------------
__global__ void k_scan_a(const int* __restrict__ counts, int* __restrict__ rs, int* __restrict__ bsum) {
    __shared__ int s[256];
    int tid = threadIdx.x, g = blockIdx.x * 256 + tid;
    int v = (g < NC) ? counts[g] : 0;
    s[tid] = v; __syncthreads();
    for (int off = 1; off < 256; off <<= 1) {
        int u = (tid >= off) ? s[tid - off] : 0;
        __syncthreads();
        s[tid] += u;
        __syncthreads();
    }
    if (g < NC) rs[g] = s[tid] - v;
    if (tid == 255) bsum[blockIdx.x] = s[255];
}

__global__ void k_scan_b(const int* __restrict__ bsum, int* __restrict__ boff) {
    __shared__ int s[1024];
    int tid = threadIdx.x;
    int v = (tid < SCAN_NB) ? bsum[tid] : 0;
    s[tid] = v; __syncthreads();
    for (int off = 1; off < 1024; off <<= 1) {
        int u = (tid >= off) ? s[tid - off] : 0;
        __syncthreads();
        s[tid] += u;
        __syncthreads();
    }
    if (tid < SCAN_NB) boff[tid] = s[tid] - v;
}

__global__ void k_scatter(const int* __restrict__ src, const int* __restrict__ dst,
                          const int* __restrict__ rs, const int* __restrict__ boff,
                          const int* __restrict__ rank, int* __restrict__ src_csr) {
    int e = blockIdx.x * 256 + threadIdx.x, m = blockIdx.y;
    if (e >= NE) return;
    int idx = m * NN + dst[(size_t)m * NE + e];
    int pos = rs[idx] + boff[idx >> 8] + rank[(size_t)m * NE + e];
    src_csr[pos] = src[(size_t)m * NE + e];
}

// ---------------------------------------------------------------------------
// 4) Destination-centric GAT. 1 node/wave (150k waves), wave-uniform CSR in
//    SGPRs. 16-deep gather batch: avg degree = 16 (Poisson), so ~half the
//    nodes complete in ONE latency exposure; 16 feat + 16 el gathers in
//    flight per wave. Tiers 16/8/4/scalar.
// ---------------------------------------------------------------------------
__device__ __forceinline__ void edge_body(float x, float erm, float& sm,
                                          f32x2& A01, f32x2& A23, uint2 u)
{
    float tq = x + erm;
    tq = fmaxf(tq, 0.2f * tq);
    float w = __expf(tq);
    sm += w;
    f32x2 wv; wv.x = w; wv.y = w;
    A01 += wv * bfp(u.x);
    A23 += wv * bfp(u.y);
}

__global__ __launch_bounds__(256) void k_node(
    const int* __restrict__ src_csr, const int* __restrict__ rs, const int* __restrict__ boff,
    const int* __restrict__ counts,
    const float* __restrict__ el, const float* __restrict__ er,
    const u16* __restrict__ feat, const float* __restrict__ bias, u16* __restrict__ z)
{
    const int lane = threadIdx.x & 63, wid = threadIdx.x >> 6;
    const int t = blockIdx.x * 4 + wid, m = blockIdx.y;
    if (t >= NN) return;
    const int idx  = m * NN + t;
    const int row0 = __builtin_amdgcn_readfirstlane(rs[idx] + boff[idx >> 8]);
    const int deg  = __builtin_amdgcn_readfirstlane(counts[idx]);
    const int kl   = lane >> 3;
    const int l4   = lane * 4;

    const float erm  = er[(size_t)idx * NH + kl];
    const float* elm = el + (size_t)m * NN * NH;
    const u16*   fm  = feat + (size_t)m * NN * DF;
    const int*   cs  = src_csr + row0;

    float sm = 0.f;
    f32x2 A01; A01.x = 0.f; A01.y = 0.f;
    f32x2 A23; A23.x = 0.f; A23.y = 0.f;

    int j = 0;
    // 16-deep tier: one latency exposure covers the average degree
    for (; j + 16 <= deg; j += 16) {
        int s[16];
#pragma unroll
        for (int q = 0; q < 16; q++) s[q] = __builtin_amdgcn_readfirstlane(cs[j + q]);
        float x[16];
#pragma unroll
        for (int q = 0; q < 16; q++) x[q] = elm[(size_t)s[q] * NH + kl];
        uint2 u[16];
#pragma unroll
        for (int q = 0; q < 16; q++) u[q] = *(const uint2*)(fm + (size_t)s[q] * DF + l4);
#pragma unroll
        for (int q = 0; q < 16; q++) edge_body(x[q], erm, sm, A01, A23, u[q]);
    }
    for (; j + 8 <= deg; j += 8) {
        int s[8];
#pragma unroll
        for (int q = 0; q < 8; q++) s[q] = __builtin_amdgcn_readfirstlane(cs[j + q]);
        float x[8];
#pragma unroll
        for (int q = 0; q < 8; q++) x[q] = elm[(size_t)s[q] * NH + kl];
        uint2 u[8];
#pragma unroll
        for (int q = 0; q < 8; q++) u[q] = *(const uint2*)(fm + (size_t)s[q] * DF + l4);
#pragma unroll
        for (int q = 0; q < 8; q++) edge_body(x[q], erm, sm, A01, A23, u[q]);
    }
    for (; j + 4 <= deg; j += 4) {
        int s[4];
#pragma unroll
        for (int q = 0; q < 4; q++) s[q] = __builtin_amdgcn_readfirstlane(cs[j + q]);
        float x[4];
#pragma unroll
        for (int q = 0; q < 4; q++) x[q] = elm[(size_t)s[q] * NH + kl];
        uint2 u[4];
#pragma unroll
        for (int q = 0; q < 4; q++) u[q] = *(const uint2*)(fm + (size_t)s[q] * DF + l4);
#pragma unroll
        for (int q = 0; q < 4; q++) edge_body(x[q], erm, sm, A01, A23, u[q]);
    }
    for (; j < deg; ++j) {
        int s0 = __builtin_amdgcn_readfirstlane(cs[j]);
        float x = elm[(size_t)s0 * NH + kl];
        uint2 u = *(const uint2*)(fm + (size_t)s0 * DF + l4);
        edge_body(x, erm, sm, A01, A23, u);
    }
    const float rdm = 1.f / (sm + 1e-9f);

    float4 ub = *(const float4*)(bias + m * DF + l4);
    float z0 = A01.x * rdm + ub.x, z1 = A01.y * rdm + ub.y;
    float z2 = A23.x * rdm + ub.z, z3 = A23.y * rdm + ub.w;
    z0 = z0 > 0.f ? z0 : __expf(z0) - 1.f;
    z1 = z1 > 0.f ? z1 : __expf(z1) - 1.f;
    z2 = z2 > 0.f ? z2 : __expf(z2) - 1.f;
    z3 = z3 > 0.f ? z3 : __expf(z3) - 1.f;
    uint2 o;
    o.x = (u32)f2bf(z0) | ((u32)f2bf(z1) << 16);
    o.y = (u32)f2bf(z2) | ((u32)f2bf(z3) << 16);
    *(uint2*)(z + ((size_t)m * NN + t) * DF + l4) = o;
}

// ---------------------------------------------------------------------------
// 5) Semantic attention logits via MFMA, fused fast-tanh/w2/reduce epilogue.
// ---------------------------------------------------------------------------
__global__ __launch_bounds__(256) void k_sem(
    const u16* __restrict__ z, const u16* __restrict__ W1T,
    const float* __restrict__ b1, const float* __restrict__ w2,
    float* __restrict__ w_acc)
{
    __shared__ float buck[MP];
    const int tid = threadIdx.x, lane = tid & 63, wid = tid >> 6;
    const int quad = lane >> 4, l16 = lane & 15;
    if (tid < MP) buck[tid] = 0.f;
    __syncthreads();

    const int row0 = blockIdx.x * 64 + wid * 16;
    const int arow = row0 + l16;
    const int arc  = arow < NC ? arow : NC - 1;
    const u16* ab = z + (size_t)arc * DF + quad * 8;
    bf16x8 afrag[8];
#pragma unroll
    for (int ks = 0; ks < 8; ks++) afrag[ks] = *(const bf16x8*)(ab + ks * 32);

    const u16* bb0 = W1T + (size_t)l16 * DF + quad * 8;
    float rsum[4] = {0.f, 0.f, 0.f, 0.f};
#pragma unroll
    for (int nt = 0; nt < 8; nt++) {
        f32x4 acc; acc[0]=0.f; acc[1]=0.f; acc[2]=0.f; acc[3]=0.f;
        const u16* bb = bb0 + (size_t)nt * 16 * DF;
#pragma unroll
        for (int ks = 0; ks < 8; ks++) {
            bf16x8 bfrag = *(const bf16x8*)(bb + ks * 32);
            acc = __builtin_amdgcn_mfma_f32_16x16x32_bf16(afrag[ks], bfrag, acc, 0, 0, 0);
        }
        const int col = nt * 16 + l16;
        const float bb1 = b1[col], ww2 = w2[col];
#pragma unroll
        for (int r = 0; r < 4; r++) rsum[r] += tanh_fast(acc[r] + bb1) * ww2;
    }
#pragma unroll
    for (int msk = 1; msk <= 8; msk <<= 1)
#pragma unroll
        for (int r = 0; r < 4; r++) rsum[r] += __shfl_xor(rsum[r], msk);

    if (l16 == 0) {
#pragma unroll
        for (int r = 0; r < 4; r++) {
            int g = row0 + quad * 4 + r;
            if (g < NC) atomicAdd(&buck[g / NN], rsum[r]);
        }
    }
    __syncthreads();
    if (tid < MP) atomicAdd(w_acc + tid, buck[tid]);
}

__global__ void k_beta(const float* __restrict__ w_acc, float* __restrict__ beta) {
    if (threadIdx.x == 0 && blockIdx.x == 0) {
        float w0 = w_acc[0] / (float)NN, w1 = w_acc[1] / (float)NN, w2 = w_acc[2] / (float)NN;
        float mx = fmaxf(w0, fmaxf(w1, w2));
        float e0 = expf(w0 - mx), e1 = expf(w1 - mx), e2 = expf(w2 - mx);
        float s = e0 + e1 + e2;
        beta[0] = e0 / s; beta[1] = e1 / s; beta[2] = e2 / s;
    }
}

__global__ __launch_bounds__(256) void k_combine(
    const u16* __restrict__ z, const float* __restrict__ beta, float* __restrict__ out)
{
    size_t i = ((size_t)blockIdx.x * 256 + threadIdx.x) * 8;
    if (i >= (size_t)NN * DF) return;
    float b0 = beta[0], b1 = beta[1], b2 = beta[2];
    uint4 u0 = *(const uint4*)(z + i);
    uint4 u1 = *(const uint4*)(z + (size_t)NN * DF + i);
    uint4 u2 = *(const uint4*)(z + 2 * (size_t)NN * DF + i);
    float4 oa, ob;
    oa.x = b0 * bf2f((u16)(u0.x & 0xffff)) + b1 * bf2f((u16)(u1.x & 0xffff)) + b2 * bf2f((u16)(u2.x & 0xffff));
    oa.y = b0 * bf2f((u16)(u0.x >> 16))    + b1 * bf2f((u16)(u1.x >> 16))    + b2 * bf2f((u16)(u2.x >> 16));
    oa.z = b0 * bf2f((u16)(u0.y & 0xffff)) + b1 * bf2f((u16)(u1.y & 0xffff)) + b2 * bf2f((u16)(u2.y & 0xffff));
    oa.w = b0 * bf2f((u16)(u0.y >> 16))    + b1 * bf2f((u16)(u1.y >> 16))    + b2 * bf2f((u16)(u2.y >> 16));
    ob.x = b0 * bf2f((u16)(u0.z & 0xffff)) + b1 * bf2f((u16)(u1.z & 0xffff)) + b2 * bf2f((u16)(u2.z & 0xffff));
    ob.y = b0 * bf2f((u16)(u0.z >> 16))    + b1 * bf2f((u16)(u1.z >> 16))    + b2 * bf2f((u16)(u2.z >> 16));
    ob.z = b0 * bf2f((u16)(u0.w & 0xffff)) + b1 * bf2f((u16)(u1.w & 0xffff)) + b2 * bf2f((u16)(u2.w & 0xffff));
    ob.w = b0 * bf2f((u16)(u0.w >> 16))    + b1 * bf2f((u16)(u1.w >> 16))    + b2 * bf2f((u16)(u2.w >> 16));
    *(float4*)(out + i) = oa;
    *(float4*)(out + i + 4) = ob;
}

// ---------------------------------------------------------------------------
extern "C" void kernel_launch(void* const* d_in, const int* in_sizes, int n_in,
                              void* d_out, int out_size, void* d_ws, size_t ws_size,
                              hipStream_t stream)
{
    const float* h    = (const float*)d_in[0];
    const float* Wg   = (const float*)d_in[1];
    const float* al   = (const float*)d_in[2];
    const float* ar   = (const float*)d_in[3];
    const float* bias = (const float*)d_in[4];
    const float* W1   = (const float*)d_in[5];
    const float* b1   = (const float*)d_in[6];
    const float* w2   = (const float*)d_in[7];
    const int*   src  = (const int*)d_in[8];
    const int*   dst  = (const int*)d_in[9];
    float* out = (float*)d_out;

    char* w = (char*)d_ws;
    size_t off = 0;
    auto take = [&](size_t b) -> char* {
        char* p = w + off;
        off = (off + b + 255) & ~(size_t)255;
        return p;
    };
    u16*   feat    = (u16*)  take((size_t)MP * NN * DF * 2);
    u16*   zbuf    = (u16*)  take((size_t)MP * NN * DF * 2);
    u16*   hb      = (u16*)  take((size_t)NN * DIN * 2);
    u16*   WgT     = (u16*)  take((size_t)MP * DF * DIN * 2);
    u16*   W1T     = (u16*)  take((size_t)HID * DF * 2);
    u16*   WALT    = (u16*)  take((size_t)MP * 16 * DIN * 2);
    float* el      = (float*)take((size_t)MP * NN * NH * 4);
    float* er      = (float*)take((size_t)MP * NN * NH * 4);
    int*   counts  = (int*)  take((size_t)NC * 4);
    int*   rowst   = (int*)  take((size_t)NC * 4);
    int*   src_csr = (int*)  take((size_t)MP * NE * 4);
    int*   bsum    = (int*)  take(1024 * 4);
    int*   boff    = (int*)  take(1024 * 4);
    float* w_acc   = (float*)take(64);
    float* beta    = (float*)take(64);
    // rank is dead before k_node writes zbuf -> alias it onto zbuf
    int*   rank    = (int*)zbuf;

    hipMemsetAsync(counts, 0, (size_t)NC * 4, stream);
    hipMemsetAsync(w_acc, 0, 64, stream);

    k_cvt_count<<<CVT_NB + MP * CNT_NB, 256, 0, stream>>>(
        h, Wg, W1, al, ar, hb, WgT, W1T, WALT, dst, counts, rank);

    k_gemm_feat<<<dim3((NN + 63) / 64, MP), 256, 0, stream>>>(hb, WgT, WALT, feat, el, er);
    k_scan_a<<<SCAN_NB, 256, 0, stream>>>(counts, rowst, bsum);
    k_scan_b<<<1, 1024, 0, stream>>>(bsum, boff);
    k_scatter<<<dim3(CNT_NB, MP), 256, 0, stream>>>(src, dst, rowst, boff, rank, src_csr);
    k_node<<<dim3((NN + 3) / 4, MP), 256, 0, stream>>>(src_csr, rowst, boff, counts, el, er, feat, bias, zbuf);
    k_sem<<<(NC + 63) / 64, 256, 0, stream>>>(zbuf, W1T, b1, w2, w_acc);
    k_beta<<<1, 64, 0, stream>>>(w_acc, beta);
    k_combine<<<(NN * DF / 8 + 255) / 256, 256, 0, stream>>>(zbuf, beta, out);
}